// Round 1
// baseline (359.724 us; speedup 1.0000x reference)
//
#include <hip/hip_runtime.h>

namespace {

constexpr int D_DIM     = 512;
constexpr int ENT_LEN   = 39;
constexpr int N_MOVES   = 896;

// entity column indices
constexpr int C_SPECIES = 0, C_ABILITY = 1, C_ITEM = 2, C_LEVEL = 3, C_HP = 4;
constexpr int C_GENDER = 5, C_STATUS = 6, C_CB = 7, C_TRAP = 8, C_NEWSW = 9;
constexpr int C_TOXIC = 10, C_SLEEP = 11, C_FAINT = 12, C_ACTIVE = 13;
constexpr int C_BOOST0 = 14, C_MOVEID0 = 21, C_MOVEPP0 = 25, C_VOL0 = 30;

__global__ __launch_bounds__(256) void entity_encoder_kernel(
    const int*   __restrict__ ent,
    const float* __restrict__ W_species, const float* __restrict__ b_species,
    const float* __restrict__ W_ability, const float* __restrict__ b_ability,
    const float* __restrict__ W_item,    const float* __restrict__ b_item,
    const float* __restrict__ W_moveset, const float* __restrict__ b_moveset,
    const float* __restrict__ W_level,   const float* __restrict__ b_level,
    const float* __restrict__ W_hp,      const float* __restrict__ b_hp,
    const float* __restrict__ W_vol,     const float* __restrict__ b_vol,
    const float* __restrict__ W_feats,   const float* __restrict__ b_feats,
    const float* __restrict__ W_bool,    const float* __restrict__ b_bool,
    float* __restrict__ out_emb, float* __restrict__ out_mask, int n)
{
    const int e_idx = (blockIdx.x << 1) | (threadIdx.x >> 7); // 2 entities / block
    if (e_idx >= n) return;
    const int t = threadIdx.x & 127;       // 128 threads per entity
    const int d = t << 2;                  // float4 slice of D=512
    const int* __restrict__ e = ent + e_idx * ENT_LEN;

    float4 acc = make_float4(0.f, 0.f, 0.f, 0.f);

#define ADDROW(W, row) do {                                                        \
        const float4 v_ = *reinterpret_cast<const float4*>((W) + ((size_t)(row))*D_DIM + d); \
        acc.x += v_.x; acc.y += v_.y; acc.z += v_.z; acc.w += v_.w;                \
    } while (0)
#define FMAROW(W, row, s) do {                                                     \
        const float4 v_ = *reinterpret_cast<const float4*>((W) + ((size_t)(row))*D_DIM + d); \
        const float s_ = (s);                                                      \
        acc.x = fmaf(s_, v_.x, acc.x); acc.y = fmaf(s_, v_.y, acc.y);              \
        acc.z = fmaf(s_, v_.z, acc.z); acc.w = fmaf(s_, v_.w, acc.w);              \
    } while (0)

    // ---- species / ability / item embeddings
    const int sp = e[C_SPECIES];
    ADDROW(W_species, sp);
    ADDROW(W_ability, e[C_ABILITY]);
    ADDROW(W_item,    e[C_ITEM]);

    // ---- moveset: sum W_mv[mv] + pp * W_pp[mv]
    #pragma unroll
    for (int m = 0; m < 4; ++m) {
        const int mv = e[C_MOVEID0 + m];
        ADDROW(W_moveset, mv);
        const float pp = (float)e[C_MOVEPP0 + m] * (1.0f / 1023.0f);
        FMAROW(W_moveset, N_MOVES + mv, pp);
    }

    // ---- level bits (7) and hp bits (10): branches are uniform per entity
    const int lv = e[C_LEVEL];
    #pragma unroll
    for (int b = 0; b < 7; ++b)
        if ((lv >> b) & 1) ADDROW(W_level, b);
    const int hp = e[C_HP];
    #pragma unroll
    for (int b = 0; b < 10; ++b)
        if ((hp >> b) & 1) ADDROW(W_hp, b);

    // ---- volatiles: 9 columns x 4 bits
    #pragma unroll
    for (int j = 0; j < 9; ++j) {
        const int v = e[C_VOL0 + j];
        #pragma unroll
        for (int b = 0; b < 4; ++b)
            if ((v >> b) & 1) ADDROW(W_vol, j * 4 + b);
    }

    // ---- continuous feats: [lv/100, hp/1023, 0.5*boost_i]
    FMAROW(W_feats, 0, (float)lv * (1.0f / 100.0f));
    FMAROW(W_feats, 1, (float)hp * (1.0f / 1023.0f));
    #pragma unroll
    for (int i = 0; i < 7; ++i)
        FMAROW(W_feats, 2 + i, 0.5f * (float)e[C_BOOST0 + i]);

    // ---- categorical one-hots into W_bool (offsets per reference concat order)
    ADDROW(W_bool,      e[C_GENDER]);        // @0,  4
    ADDROW(W_bool,  4 + e[C_STATUS]);        // @4,  8
    ADDROW(W_bool, 12 + e[C_CB]);            // @12, 2
    ADDROW(W_bool, 14 + e[C_TRAP]);          // @14, 2
    ADDROW(W_bool, 16 + e[C_NEWSW]);         // @16, 2
    ADDROW(W_bool, 18 + e[C_TOXIC]);         // @18, 8
    ADDROW(W_bool, 26 + e[C_SLEEP]);         // @26, 4
    ADDROW(W_bool, 30 + e[C_FAINT]);         // @30, 2
    ADDROW(W_bool, 32 + e[C_ACTIVE]);        // @32, 2
    #pragma unroll
    for (int i = 0; i < 7; ++i)              // boosts @34+13i, 13 each
        ADDROW(W_bool, 34 + 13 * i + e[C_BOOST0 + i] + 6);

    // ---- biases (all added unconditionally in the reference)
    ADDROW(b_species, 0); ADDROW(b_ability, 0); ADDROW(b_item, 0);
    ADDROW(b_moveset, 0); ADDROW(b_level, 0);   ADDROW(b_hp, 0);
    ADDROW(b_vol, 0);     ADDROW(b_feats, 0);   ADDROW(b_bool, 0);

#undef ADDROW
#undef FMAROW

    // ---- mask + store
    const bool mask = !(sp == 0 || sp == 1);
    if (!mask) acc = make_float4(0.f, 0.f, 0.f, 0.f);
    *reinterpret_cast<float4*>(out_emb + (size_t)e_idx * D_DIM + d) = acc;
    if (t == 0) out_mask[e_idx] = mask ? 1.0f : 0.0f;
}

} // namespace

extern "C" void kernel_launch(void* const* d_in, const int* in_sizes, int n_in,
                              void* d_out, int out_size, void* d_ws, size_t ws_size,
                              hipStream_t stream) {
    const int n = in_sizes[0] / ENT_LEN;

    const int*   ent  = (const int*)  d_in[0];
    const float* Wsp  = (const float*)d_in[1];
    const float* bsp  = (const float*)d_in[2];
    const float* Wab  = (const float*)d_in[3];
    const float* bab  = (const float*)d_in[4];
    const float* Wit  = (const float*)d_in[5];
    const float* bit_ = (const float*)d_in[6];
    const float* Wmv  = (const float*)d_in[7];
    const float* bmv  = (const float*)d_in[8];
    const float* Wlv  = (const float*)d_in[9];
    const float* blv  = (const float*)d_in[10];
    const float* Whp  = (const float*)d_in[11];
    const float* bhp  = (const float*)d_in[12];
    const float* Wvo  = (const float*)d_in[13];
    const float* bvo  = (const float*)d_in[14];
    const float* Wft  = (const float*)d_in[15];
    const float* bft  = (const float*)d_in[16];
    const float* Wbo  = (const float*)d_in[17];
    const float* bbo  = (const float*)d_in[18];

    float* out_emb  = (float*)d_out;
    float* out_mask = out_emb + (size_t)n * D_DIM;

    const int blocks = (n + 1) / 2;   // 2 entities per 256-thread block
    entity_encoder_kernel<<<blocks, 256, 0, stream>>>(
        ent, Wsp, bsp, Wab, bab, Wit, bit_, Wmv, bmv, Wlv, blv,
        Whp, bhp, Wvo, bvo, Wft, bft, Wbo, bbo, out_emb, out_mask, n);
}

// Round 2
// 110.251 us; speedup vs baseline: 3.2628x; 3.2628x over previous
//
#include <hip/hip_runtime.h>

namespace {

constexpr int D_DIM   = 512;
constexpr int ENT_LEN = 39;
constexpr int N_MOVES = 896;

// ---- fused bf16 table row offsets (rows of 512 bf16 = 1 KB each) ----
constexpr int R_SP    = 0;                 // 1280 rows: W_species[r] + sum(all 9 biases)
constexpr int R_AB    = 1280;              // 320
constexpr int R_IT    = 1600;              // 1024
constexpr int R_MV    = 2624;              // 1792 (mv rows then pp rows)
constexpr int R_LV    = 4416;              // 101: bits(lv)@W_level + (lv/100)W_feats[0]
constexpr int R_HP    = 4517;              // 1024: bits(hp)@W_hp + (hp/1023)W_feats[1]
constexpr int R_VOL   = 5541;              // 4*256 pair tables + 16 single = 1040
constexpr int R_BST   = 6581;              // 3*169 pair tables + 13 single = 520
constexpr int R_GS    = 7101;              // 32: gender x status
constexpr int R_FLAGS = 7133;              // 32: cb,trap,newsw,faint,active bits
constexpr int R_TS    = 7165;              // 32: toxic x sleep
constexpr int R_TOTAL = 7197;
constexpr size_t WS_NEED = (size_t)R_TOTAL * D_DIM * sizeof(unsigned short);

__device__ inline unsigned short f2bf(float f) {      // round-to-nearest-even
    unsigned u = __float_as_uint(f);
    u += 0x7fffu + ((u >> 16) & 1u);
    return (unsigned short)(u >> 16);
}

// ---------------- table precompute: 1 row per block, 2 dims per thread ----------------
__global__ __launch_bounds__(256) void build_tables(
    const float* __restrict__ Wsp, const float* __restrict__ bsp,
    const float* __restrict__ Wab, const float* __restrict__ bab,
    const float* __restrict__ Wit, const float* __restrict__ bit_,
    const float* __restrict__ Wmv, const float* __restrict__ bmv,
    const float* __restrict__ Wlv, const float* __restrict__ blv,
    const float* __restrict__ Whp, const float* __restrict__ bhp,
    const float* __restrict__ Wvo, const float* __restrict__ bvo,
    const float* __restrict__ Wft, const float* __restrict__ bft,
    const float* __restrict__ Wbo, const float* __restrict__ bbo,
    unsigned short* __restrict__ T)
{
    const int r = blockIdx.x;
    const int d = threadIdx.x << 1;
    float vx = 0.f, vy = 0.f;
    auto add = [&](const float* W, int row, float s) {
        const float2 w = *reinterpret_cast<const float2*>(W + (size_t)row * D_DIM + d);
        vx = fmaf(s, w.x, vx); vy = fmaf(s, w.y, vy);
    };
    if (r < R_AB) {
        add(Wsp, r, 1.f);
        add(bsp, 0, 1.f); add(bab, 0, 1.f); add(bit_, 0, 1.f);
        add(bmv, 0, 1.f); add(blv, 0, 1.f); add(bhp, 0, 1.f);
        add(bvo, 0, 1.f); add(bft, 0, 1.f); add(bbo, 0, 1.f);
    } else if (r < R_IT) {
        add(Wab, r - R_AB, 1.f);
    } else if (r < R_MV) {
        add(Wit, r - R_IT, 1.f);
    } else if (r < R_LV) {
        add(Wmv, r - R_MV, 1.f);
    } else if (r < R_HP) {
        const int lv = r - R_LV;
        for (int b = 0; b < 7; ++b) if ((lv >> b) & 1) add(Wlv, b, 1.f);
        add(Wft, 0, (float)lv * (1.f / 100.f));
    } else if (r < R_VOL) {
        const int hp = r - R_HP;
        for (int b = 0; b < 10; ++b) if ((hp >> b) & 1) add(Whp, b, 1.f);
        add(Wft, 1, (float)hp * (1.f / 1023.f));
    } else if (r < R_BST) {
        const int rr = r - R_VOL;
        if (rr < 1024) {                       // pair table p: code = v[2p] | v[2p+1]<<4
            const int p = rr >> 8, code = rr & 255, va = code & 15, vb = code >> 4;
            for (int b = 0; b < 4; ++b) {
                if ((va >> b) & 1) add(Wvo, 8 * p + b, 1.f);
                if ((vb >> b) & 1) add(Wvo, 8 * p + 4 + b, 1.f);
            }
        } else {                               // single col 8
            const int code = rr - 1024;
            for (int b = 0; b < 4; ++b) if ((code >> b) & 1) add(Wvo, 32 + b, 1.f);
        }
    } else if (r < R_GS) {
        const int rr = r - R_BST;
        if (rr < 507) {                        // pair q: idx = (b2q+6) + 13*(b2q1+6)
            const int q = rr / 169, code = rr % 169, ba = code % 13, bb = code / 13;
            add(Wbo, 34 + 26 * q + ba, 1.f);
            add(Wbo, 34 + 26 * q + 13 + bb, 1.f);
            add(Wft, 2 + 2 * q, 0.5f * (float)(ba - 6));
            add(Wft, 3 + 2 * q, 0.5f * (float)(bb - 6));
        } else {                               // single boost 6
            const int code = rr - 507;
            add(Wbo, 34 + 78 + code, 1.f);
            add(Wft, 8, 0.5f * (float)(code - 6));
        }
    } else if (r < R_FLAGS) {
        const int code = r - R_GS;             // g*8 + s
        add(Wbo, code >> 3, 1.f);
        add(Wbo, 4 + (code & 7), 1.f);
    } else if (r < R_TS) {
        const int code = r - R_FLAGS;          // cb*16+tr*8+ns*4+fa*2+ac
        add(Wbo, 12 + ((code >> 4) & 1), 1.f);
        add(Wbo, 14 + ((code >> 3) & 1), 1.f);
        add(Wbo, 16 + ((code >> 2) & 1), 1.f);
        add(Wbo, 30 + ((code >> 1) & 1), 1.f);
        add(Wbo, 32 + (code & 1), 1.f);
    } else {
        const int code = r - R_TS;             // tox*4 + sl
        add(Wbo, 18 + (code >> 2), 1.f);
        add(Wbo, 26 + (code & 3), 1.f);
    }
    ushort2 o; o.x = f2bf(vx); o.y = f2bf(vy);
    *reinterpret_cast<ushort2*>(T + (size_t)r * D_DIM + d) = o;
}

// ---------------- main encode: 1 wave per entity, 8 dims per lane ----------------
__global__ __launch_bounds__(256) void encode_kernel(
    const int* __restrict__ ent, const unsigned short* __restrict__ T,
    float* __restrict__ out_emb, float* __restrict__ out_mask, int n)
{
    const int e4 = (blockIdx.x << 2) | (threadIdx.x >> 6);
    if (e4 >= n) return;
    const int e_idx = __builtin_amdgcn_readfirstlane(e4);  // wave-uniform -> SGPR
    const int t = threadIdx.x & 63;
    const int* __restrict__ e = ent + (size_t)e_idx * ENT_LEN;
    const uint4* __restrict__ Tq = reinterpret_cast<const uint4*>(T);

    float acc[8] = {0.f, 0.f, 0.f, 0.f, 0.f, 0.f, 0.f, 0.f};

    auto ADD = [&](int row) {
        const uint4 u = Tq[((size_t)row << 6) + t];
        acc[0] += __uint_as_float(u.x << 16);
        acc[1] += __uint_as_float(u.x & 0xffff0000u);
        acc[2] += __uint_as_float(u.y << 16);
        acc[3] += __uint_as_float(u.y & 0xffff0000u);
        acc[4] += __uint_as_float(u.z << 16);
        acc[5] += __uint_as_float(u.z & 0xffff0000u);
        acc[6] += __uint_as_float(u.w << 16);
        acc[7] += __uint_as_float(u.w & 0xffff0000u);
    };
    auto FMA = [&](int row, float s) {
        const uint4 u = Tq[((size_t)row << 6) + t];
        acc[0] = fmaf(s, __uint_as_float(u.x << 16),          acc[0]);
        acc[1] = fmaf(s, __uint_as_float(u.x & 0xffff0000u),  acc[1]);
        acc[2] = fmaf(s, __uint_as_float(u.y << 16),          acc[2]);
        acc[3] = fmaf(s, __uint_as_float(u.y & 0xffff0000u),  acc[3]);
        acc[4] = fmaf(s, __uint_as_float(u.z << 16),          acc[4]);
        acc[5] = fmaf(s, __uint_as_float(u.z & 0xffff0000u),  acc[5]);
        acc[6] = fmaf(s, __uint_as_float(u.w << 16),          acc[6]);
        acc[7] = fmaf(s, __uint_as_float(u.w & 0xffff0000u),  acc[7]);
    };

    const int sp = e[0];
    ADD(R_SP + sp);                       // biases folded in here
    ADD(R_AB + e[1]);
    ADD(R_IT + e[2]);
    #pragma unroll
    for (int m = 0; m < 4; ++m) {
        const int mv = e[21 + m];
        ADD(R_MV + mv);
        FMA(R_MV + N_MOVES + mv, (float)e[25 + m] * (1.f / 1023.f));
    }
    ADD(R_LV + e[3]);
    ADD(R_HP + e[4]);
    #pragma unroll
    for (int p = 0; p < 4; ++p)
        ADD(R_VOL + (p << 8) + (e[30 + 2 * p] | (e[31 + 2 * p] << 4)));
    ADD(R_VOL + 1024 + e[38]);
    #pragma unroll
    for (int q = 0; q < 3; ++q)
        ADD(R_BST + q * 169 + (e[14 + 2 * q] + 6) + 13 * (e[15 + 2 * q] + 6));
    ADD(R_BST + 507 + e[20] + 6);
    ADD(R_GS + (e[5] << 3) + e[6]);
    ADD(R_FLAGS + (e[7] << 4) + (e[8] << 3) + (e[9] << 2) + (e[12] << 1) + e[13]);
    ADD(R_TS + (e[10] << 2) + e[11]);

    const bool mask = (sp > 1);
    float4 o0 = make_float4(acc[0], acc[1], acc[2], acc[3]);
    float4 o1 = make_float4(acc[4], acc[5], acc[6], acc[7]);
    if (!mask) { o0 = make_float4(0.f,0.f,0.f,0.f); o1 = make_float4(0.f,0.f,0.f,0.f); }
    float4* op = reinterpret_cast<float4*>(out_emb + (size_t)e_idx * D_DIM) + (t << 1);
    op[0] = o0; op[1] = o1;
    if (t == 0) out_mask[e_idx] = mask ? 1.f : 0.f;
}

// ---------------- fallback (round-0 kernel) if workspace is too small ----------------
__global__ __launch_bounds__(256) void entity_encoder_fallback(
    const int*   __restrict__ ent,
    const float* __restrict__ W_species, const float* __restrict__ b_species,
    const float* __restrict__ W_ability, const float* __restrict__ b_ability,
    const float* __restrict__ W_item,    const float* __restrict__ b_item,
    const float* __restrict__ W_moveset, const float* __restrict__ b_moveset,
    const float* __restrict__ W_level,   const float* __restrict__ b_level,
    const float* __restrict__ W_hp,      const float* __restrict__ b_hp,
    const float* __restrict__ W_vol,     const float* __restrict__ b_vol,
    const float* __restrict__ W_feats,   const float* __restrict__ b_feats,
    const float* __restrict__ W_bool,    const float* __restrict__ b_bool,
    float* __restrict__ out_emb, float* __restrict__ out_mask, int n)
{
    const int e_idx = (blockIdx.x << 1) | (threadIdx.x >> 7);
    if (e_idx >= n) return;
    const int t = threadIdx.x & 127;
    const int d = t << 2;
    const int* __restrict__ e = ent + e_idx * ENT_LEN;
    float4 acc = make_float4(0.f, 0.f, 0.f, 0.f);
#define ADDROW(W, row) do {                                                        \
        const float4 v_ = *reinterpret_cast<const float4*>((W) + ((size_t)(row))*D_DIM + d); \
        acc.x += v_.x; acc.y += v_.y; acc.z += v_.z; acc.w += v_.w;                \
    } while (0)
#define FMAROW(W, row, s) do {                                                     \
        const float4 v_ = *reinterpret_cast<const float4*>((W) + ((size_t)(row))*D_DIM + d); \
        const float s_ = (s);                                                      \
        acc.x = fmaf(s_, v_.x, acc.x); acc.y = fmaf(s_, v_.y, acc.y);              \
        acc.z = fmaf(s_, v_.z, acc.z); acc.w = fmaf(s_, v_.w, acc.w);              \
    } while (0)
    const int sp = e[0];
    ADDROW(W_species, sp); ADDROW(W_ability, e[1]); ADDROW(W_item, e[2]);
    #pragma unroll
    for (int m = 0; m < 4; ++m) {
        const int mv = e[21 + m];
        ADDROW(W_moveset, mv);
        FMAROW(W_moveset, N_MOVES + mv, (float)e[25 + m] * (1.0f / 1023.0f));
    }
    const int lv = e[3];
    #pragma unroll
    for (int b = 0; b < 7; ++b) if ((lv >> b) & 1) ADDROW(W_level, b);
    const int hp = e[4];
    #pragma unroll
    for (int b = 0; b < 10; ++b) if ((hp >> b) & 1) ADDROW(W_hp, b);
    #pragma unroll
    for (int j = 0; j < 9; ++j) {
        const int v = e[30 + j];
        #pragma unroll
        for (int b = 0; b < 4; ++b) if ((v >> b) & 1) ADDROW(W_vol, j * 4 + b);
    }
    FMAROW(W_feats, 0, (float)lv * (1.0f / 100.0f));
    FMAROW(W_feats, 1, (float)hp * (1.0f / 1023.0f));
    #pragma unroll
    for (int i = 0; i < 7; ++i) FMAROW(W_feats, 2 + i, 0.5f * (float)e[14 + i]);
    ADDROW(W_bool, e[5]); ADDROW(W_bool, 4 + e[6]); ADDROW(W_bool, 12 + e[7]);
    ADDROW(W_bool, 14 + e[8]); ADDROW(W_bool, 16 + e[9]); ADDROW(W_bool, 18 + e[10]);
    ADDROW(W_bool, 26 + e[11]); ADDROW(W_bool, 30 + e[12]); ADDROW(W_bool, 32 + e[13]);
    #pragma unroll
    for (int i = 0; i < 7; ++i) ADDROW(W_bool, 34 + 13 * i + e[14 + i] + 6);
    ADDROW(b_species, 0); ADDROW(b_ability, 0); ADDROW(b_item, 0);
    ADDROW(b_moveset, 0); ADDROW(b_level, 0);   ADDROW(b_hp, 0);
    ADDROW(b_vol, 0);     ADDROW(b_feats, 0);   ADDROW(b_bool, 0);
#undef ADDROW
#undef FMAROW
    const bool mask = !(sp == 0 || sp == 1);
    if (!mask) acc = make_float4(0.f, 0.f, 0.f, 0.f);
    *reinterpret_cast<float4*>(out_emb + (size_t)e_idx * D_DIM + d) = acc;
    if (t == 0) out_mask[e_idx] = mask ? 1.0f : 0.0f;
}

} // namespace

extern "C" void kernel_launch(void* const* d_in, const int* in_sizes, int n_in,
                              void* d_out, int out_size, void* d_ws, size_t ws_size,
                              hipStream_t stream) {
    const int n = in_sizes[0] / ENT_LEN;

    const int*   ent  = (const int*)  d_in[0];
    const float* Wsp  = (const float*)d_in[1];
    const float* bsp  = (const float*)d_in[2];
    const float* Wab  = (const float*)d_in[3];
    const float* bab  = (const float*)d_in[4];
    const float* Wit  = (const float*)d_in[5];
    const float* bit_ = (const float*)d_in[6];
    const float* Wmv  = (const float*)d_in[7];
    const float* bmv  = (const float*)d_in[8];
    const float* Wlv  = (const float*)d_in[9];
    const float* blv  = (const float*)d_in[10];
    const float* Whp  = (const float*)d_in[11];
    const float* bhp  = (const float*)d_in[12];
    const float* Wvo  = (const float*)d_in[13];
    const float* bvo  = (const float*)d_in[14];
    const float* Wft  = (const float*)d_in[15];
    const float* bft  = (const float*)d_in[16];
    const float* Wbo  = (const float*)d_in[17];
    const float* bbo  = (const float*)d_in[18];

    float* out_emb  = (float*)d_out;
    float* out_mask = out_emb + (size_t)n * D_DIM;

    if (ws_size >= WS_NEED) {
        unsigned short* T = (unsigned short*)d_ws;
        build_tables<<<R_TOTAL, 256, 0, stream>>>(
            Wsp, bsp, Wab, bab, Wit, bit_, Wmv, bmv, Wlv, blv,
            Whp, bhp, Wvo, bvo, Wft, bft, Wbo, bbo, T);
        encode_kernel<<<(n + 3) / 4, 256, 0, stream>>>(ent, T, out_emb, out_mask, n);
    } else {
        entity_encoder_fallback<<<(n + 1) / 2, 256, 0, stream>>>(
            ent, Wsp, bsp, Wab, bab, Wit, bit_, Wmv, bmv, Wlv, blv,
            Whp, bhp, Wvo, bvo, Wft, bft, Wbo, bbo, out_emb, out_mask, n);
    }
}